// Round 1
// baseline (522.132 us; speedup 1.0000x reference)
//
#include <hip/hip_runtime.h>
#include <hip/hip_bf16.h>
#include <stdint.h>
#include <math.h>

// ---------------------------------------------------------------------------
// GATNet on MI355X.
// Key insight: adj is only a mask (adj>0 <=> x_i.x_j >= 0.8*|x_i||x_j|);
// for this data the mask is ~identity, so attention is done as a sparse
// bit-mask scan + online softmax (general for any mask). Heavy lifting is
// three bf16 MFMA GEMMs (sim 47GF, Wh 94.5GF, out 4.3GF).
// ---------------------------------------------------------------------------

typedef __bf16 bf16x8 __attribute__((ext_vector_type(8)));
typedef float  f32x4  __attribute__((ext_vector_type(4)));

#define AS1C(p) ((const __attribute__((address_space(1))) void*)(p))
#define AS3(p)  ((__attribute__((address_space(3))) void*)(p))

#define MODE_BF16 0
#define MODE_SIM  1
#define MODE_F32  2

// C = A(M x K, lda) * B^T where B is (N x K, ldb), both bf16 row-major.
// 128x128 tile, BK=32, 256 threads (4 waves, 2x2 of 64x64), 16x16x32 MFMA.
// global_load_lds(16B) staging with XOR swizzle so ds_read_b128 is 2-way max.
template<int MODE>
__global__ __launch_bounds__(256, 2)
void gemm_bt(const __hip_bfloat16* __restrict__ A,
             const __hip_bfloat16* __restrict__ B,
             int lda, int ldb, int K,
             void* __restrict__ Cv, int ldc, int Nreal,
             const float* __restrict__ norms,
             unsigned* __restrict__ mask,
             long long zA, long long zB, long long zC)
{
    __shared__ __align__(16) __hip_bfloat16 As[128 * 32];
    __shared__ __align__(16) __hip_bfloat16 Bs[128 * 32];

    const int tid  = threadIdx.x;
    const int lane = tid & 63;
    const int wave = tid >> 6;
    const int m0   = blockIdx.x * 128;
    const int n0   = blockIdx.y * 128;
    const int z    = blockIdx.z;

    A += (long long)z * zA;
    B += (long long)z * zB;

    f32x4 acc[4][4];
#pragma unroll
    for (int i = 0; i < 4; ++i)
#pragma unroll
        for (int j = 0; j < 4; ++j)
#pragma unroll
            for (int k = 0; k < 4; ++k) acc[i][j][k] = 0.f;

    const int wm = wave >> 1, wn = wave & 1;
    const int q  = lane >> 4, ln = lane & 15;

    const int kIters = K >> 5;
    for (int kt = 0; kt < kIters; ++kt) {
        __syncthreads();
#pragma unroll
        for (int p = 0; p < 2; ++p) {
            const int t   = p * 256 + tid;
            const int row = t >> 2;
            const int kb  = (t & 3) ^ ((t >> 3) & 3);   // XOR swizzle slot
            const __hip_bfloat16* ga = A + (long long)(m0 + row) * lda + kt * 32 + kb * 8;
            const __hip_bfloat16* gb = B + (long long)(n0 + row) * ldb + kt * 32 + kb * 8;
            // wave-uniform LDS base; HW writes base + lane*16
            __hip_bfloat16* sa = As + (p * 256 + wave * 64) * 8;
            __hip_bfloat16* sb = Bs + (p * 256 + wave * 64) * 8;
            __builtin_amdgcn_global_load_lds(AS1C(ga), AS3(sa), 16, 0, 0);
            __builtin_amdgcn_global_load_lds(AS1C(gb), AS3(sb), 16, 0, 0);
        }
        __syncthreads();

        bf16x8 afr[4], bfr[4];
#pragma unroll
        for (int rg = 0; rg < 4; ++rg) {
            const int r = wm * 64 + rg * 16 + ln;
            const int s = q ^ ((r >> 1) & 3);
            afr[rg] = *(const bf16x8*)(As + r * 32 + s * 8);
        }
#pragma unroll
        for (int cg = 0; cg < 4; ++cg) {
            const int r = wn * 64 + cg * 16 + ln;
            const int s = q ^ ((r >> 1) & 3);
            bfr[cg] = *(const bf16x8*)(Bs + r * 32 + s * 8);
        }
#pragma unroll
        for (int rg = 0; rg < 4; ++rg)
#pragma unroll
            for (int cg = 0; cg < 4; ++cg)
                acc[rg][cg] = __builtin_amdgcn_mfma_f32_16x16x32_bf16(
                    afr[rg], bfr[cg], acc[rg][cg], 0, 0, 0);
    }

    // epilogue: C/D layout col=lane&15, row=quad*4+reg (m89/m91-verified)
#pragma unroll
    for (int rg = 0; rg < 4; ++rg) {
#pragma unroll
        for (int cg = 0; cg < 4; ++cg) {
#pragma unroll
            for (int i = 0; i < 4; ++i) {
                const int row = m0 + wm * 64 + rg * 16 + q * 4 + i;
                const int col = n0 + wn * 64 + cg * 16 + ln;
                const float v = acc[rg][cg][i];
                if (MODE == MODE_BF16) {
                    __hip_bfloat16* C = (__hip_bfloat16*)Cv + (long long)z * zC;
                    C[(long long)row * ldc + col] = __float2bfloat16(v);
                } else if (MODE == MODE_SIM) {
                    if (v >= 0.8f * norms[row] * norms[col])
                        atomicOr(&mask[row * 128 + (col >> 5)], 1u << (col & 31));
                } else {
                    if (col < Nreal) {
                        float* C = (float*)Cv + (long long)z * zC;
                        C[(long long)row * ldc + col] = v;
                    }
                }
            }
        }
    }
}

// x (4096x1386 f32) -> x_bf (4096x1408 bf16, zero-pad) + row norms
__global__ void convert_x(const float* __restrict__ x,
                          __hip_bfloat16* __restrict__ xb,
                          float* __restrict__ norms)
{
    const int i = blockIdx.x, tid = threadIdx.x;
    float ss = 0.f;
    for (int c = tid; c < 1408; c += 256) {
        float v = (c < 1386) ? x[(long long)i * 1386 + c] : 0.f;
        xb[(long long)i * 1408 + c] = __float2bfloat16(v);
        ss += v * v;
    }
    for (int off = 32; off; off >>= 1) ss += __shfl_down(ss, off);
    __shared__ float red[4];
    if ((tid & 63) == 0) red[tid >> 6] = ss;
    __syncthreads();
    if (tid == 0) norms[i] = fmaxf(sqrtf(red[0] + red[1] + red[2] + red[3]), 1e-12f);
}

// src (K x N f32) -> dst (Npad x Kpad bf16) transposed, zero-pad; batched
__global__ void transpose_bf(const float* __restrict__ src,
                             __hip_bfloat16* __restrict__ dst,
                             int K, int N, int Kpad, int Npad,
                             long long sStride, long long dStride)
{
    __shared__ float ts[32][33];
    const int b  = blockIdx.z;
    const int k0 = blockIdx.x * 32;
    const int n0 = blockIdx.y * 32;
    const int tx = threadIdx.x, ty = threadIdx.y;
    const float* s = src + b * sStride;
    __hip_bfloat16* d = dst + b * dStride;
#pragma unroll
    for (int i = 0; i < 4; ++i) {
        const int k = k0 + ty + i * 8;
        const int n = n0 + tx;
        ts[ty + i * 8][tx] = (k < K && n < N) ? s[(long long)k * N + n] : 0.f;
    }
    __syncthreads();
#pragma unroll
    for (int i = 0; i < 4; ++i) {
        const int n  = n0 + ty + i * 8;
        const int kk = k0 + tx;
        if (n < Npad && kk < Kpad)
            d[(long long)n * Kpad + kk] = __float2bfloat16(ts[tx][ty + i * 8]);
    }
}

// f1/f2 per row per head from bf16 Wh
__global__ void head_f1f2(const __hip_bfloat16* __restrict__ Wh,
                          const float* __restrict__ a_att,
                          float2* __restrict__ f12, int head_base)
{
    const int i = blockIdx.x, hl = blockIdx.y, tid = threadIdx.x;
    const int h = head_base + hl;
    const __hip_bfloat16* w = Wh + ((long long)hl * 4096 + i) * 1024;
    const float* a1 = a_att + (long long)h * 2048;
    const float* a2 = a1 + 1024;
    float s1 = 0.f, s2 = 0.f;
#pragma unroll
    for (int qq = 0; qq < 4; ++qq) {
        const int c = tid + qq * 256;
        const float v = __bfloat162float(w[c]);
        s1 += v * a1[c];
        s2 += v * a2[c];
    }
    for (int off = 32; off; off >>= 1) { s1 += __shfl_down(s1, off); s2 += __shfl_down(s2, off); }
    __shared__ float r1[4], r2[4];
    if ((tid & 63) == 0) { r1[tid >> 6] = s1; r2[tid >> 6] = s2; }
    __syncthreads();
    if (tid == 0) {
        float2 o;
        o.x = r1[0] + r1[1] + r1[2] + r1[3];
        o.y = r2[0] + r2[1] + r2[2] + r2[3];
        f12[(long long)h * 4096 + i] = o;
    }
}

// masked online-softmax attention + ELU -> hout slice (bf16)
__global__ void attn_head(const __hip_bfloat16* __restrict__ Wh,
                          const float2* __restrict__ f12,
                          const unsigned* __restrict__ mask,
                          __hip_bfloat16* __restrict__ hout,
                          int head_base, int BH)
{
    const int i = blockIdx.x, hl = blockIdx.y, tid = threadIdx.x;
    const int h = head_base + hl;
    const float2* f = f12 + (long long)h * 4096;
    const float f1 = f[i].x;
    const unsigned* mrow = mask + (long long)i * 128;
    const __hip_bfloat16* WhH = Wh + (long long)hl * 4096 * 1024;
    float m = -INFINITY, l = 0.f;
    float a0 = 0.f, a1 = 0.f, a2 = 0.f, a3 = 0.f;
    for (int w = 0; w < 128; ++w) {
        unsigned bits = mrow[w];
        while (bits) {
            const int j = w * 32 + __builtin_ctz(bits);
            bits &= bits - 1;
            float e = f1 + f[j].y;
            e = e > 0.f ? e : 0.2f * e;           // leaky_relu 0.2
            float wgt;
            if (e > m) {
                const float sc = __expf(m - e);   // 0 on first iter
                l *= sc; a0 *= sc; a1 *= sc; a2 *= sc; a3 *= sc;
                m = e; wgt = 1.f;
            } else {
                wgt = __expf(e - m);
            }
            l += wgt;
            const __hip_bfloat16* wj = WhH + (long long)j * 1024;
            a0 += wgt * __bfloat162float(wj[tid]);
            a1 += wgt * __bfloat162float(wj[tid + 256]);
            a2 += wgt * __bfloat162float(wj[tid + 512]);
            a3 += wgt * __bfloat162float(wj[tid + 768]);
        }
    }
    const float inv = 1.f / l;
    __hip_bfloat16* o = hout + (long long)i * (BH * 1024) + (long long)hl * 1024;
    float v;
    v = a0 * inv; v = v > 0.f ? v : (__expf(v) - 1.f); o[tid]       = __float2bfloat16(v);
    v = a1 * inv; v = v > 0.f ? v : (__expf(v) - 1.f); o[tid + 256] = __float2bfloat16(v);
    v = a2 * inv; v = v > 0.f ? v : (__expf(v) - 1.f); o[tid + 512] = __float2bfloat16(v);
    v = a3 * inv; v = v > 0.f ? v : (__expf(v) - 1.f); o[tid + 768] = __float2bfloat16(v);
}

// sum 8 split-K parts -> Cout; fused f1o/f2o dot products (64 threads = 1 wave)
__global__ void out_reduce_f(const float* __restrict__ parts,
                             const float* __restrict__ a_out,
                             float* __restrict__ Cout,
                             float* __restrict__ f1o,
                             float* __restrict__ f2o)
{
    const int i = blockIdx.x, c = threadIdx.x;
    float v = 0.f;
#pragma unroll
    for (int z = 0; z < 8; ++z) v += parts[(long long)z * 4096 * 64 + (long long)i * 64 + c];
    Cout[(long long)i * 64 + c] = v;
    float s1 = v * a_out[c];
    float s2 = v * a_out[64 + c];
    for (int off = 32; off; off >>= 1) { s1 += __shfl_down(s1, off); s2 += __shfl_down(s2, off); }
    if (c == 0) { f1o[i] = s1; f2o[i] = s2; }
}

// final masked attention over Cout + tanh -> out (f32)
__global__ void attn_out(const float* __restrict__ Cout,
                         const float* __restrict__ f1o,
                         const float* __restrict__ f2o,
                         const unsigned* __restrict__ mask,
                         float* __restrict__ out)
{
    const int i = blockIdx.x, c = threadIdx.x;
    const float f1 = f1o[i];
    const unsigned* mrow = mask + (long long)i * 128;
    float m = -INFINITY, l = 0.f, acc = 0.f;
    for (int w = 0; w < 128; ++w) {
        unsigned bits = mrow[w];
        while (bits) {
            const int j = w * 32 + __builtin_ctz(bits);
            bits &= bits - 1;
            float e = f1 + f2o[j];
            e = e > 0.f ? e : 0.2f * e;
            float wgt;
            if (e > m) { const float sc = __expf(m - e); l *= sc; acc *= sc; m = e; wgt = 1.f; }
            else       { wgt = __expf(e - m); }
            l += wgt;
            acc += wgt * Cout[(long long)j * 64 + c];
        }
    }
    out[(long long)i * 64 + c] = tanhf(acc / l);
}

extern "C" void kernel_launch(void* const* d_in, const int* in_sizes, int n_in,
                              void* d_out, int out_size, void* d_ws, size_t ws_size,
                              hipStream_t stream)
{
    (void)in_sizes; (void)n_in; (void)out_size;
    const float* x     = (const float*)d_in[0];
    const float* W_att = (const float*)d_in[1];
    const float* a_att = (const float*)d_in[2];
    const float* W_out = (const float*)d_in[3];
    const float* a_out = (const float*)d_in[4];
    float* out = (float*)d_out;

    char* ws = (char*)d_ws;
    size_t off = 0;
    auto alloc = [&](size_t bytes) -> void* {
        void* p = ws + off;
        off += (bytes + 255) & ~(size_t)255;
        return p;
    };

    __hip_bfloat16* x_bf  = (__hip_bfloat16*)alloc(4096LL * 1408 * 2);
    __hip_bfloat16* Wt_bf = (__hip_bfloat16*)alloc(8LL * 1024 * 1408 * 2);
    __hip_bfloat16* WoutT = (__hip_bfloat16*)alloc(128LL * 8192 * 2);
    float*          norms = (float*)alloc(4096 * 4);
    unsigned*       mask  = (unsigned*)alloc(4096LL * 128 * 4);
    float2*         f12   = (float2*)alloc(8LL * 4096 * 8);
    float*          parts = (float*)alloc(8LL * 4096 * 64 * 4);
    float*          Cout  = (float*)alloc(4096LL * 64 * 4);
    float*          f1o   = (float*)alloc(4096 * 4);
    float*          f2o   = (float*)alloc(4096 * 4);
    const size_t statics = off;

    // pick head-batch size BH so Wh_batch + hout_batch fit in remaining ws
    int BH = 8;
    while (BH > 1 && statics + (size_t)BH * 2 * 8388608ULL + 512 > ws_size) BH >>= 1;
    if (statics + (size_t)BH * 2 * 8388608ULL + 512 > ws_size) return; // ws too small
    __hip_bfloat16* Wh_b   = (__hip_bfloat16*)alloc((size_t)BH * 4096 * 1024 * 2);
    __hip_bfloat16* hout_b = (__hip_bfloat16*)alloc((size_t)BH * 4096 * 1024 * 2);

    hipMemsetAsync(mask, 0, 4096LL * 128 * 4, stream);

    convert_x<<<4096, 256, 0, stream>>>(x, x_bf, norms);
    transpose_bf<<<dim3(44, 32, 8), dim3(32, 8), 0, stream>>>(
        W_att, Wt_bf, 1386, 1024, 1408, 1024, 1386LL * 1024, 1024LL * 1408);
    transpose_bf<<<dim3(256, 4, 1), dim3(32, 8), 0, stream>>>(
        W_out, WoutT, 8192, 64, 8192, 128, 0, 0);

    // adjacency mask: G = x_bf @ x_bf^T, bit set where G >= 0.8*n_i*n_j
    gemm_bt<MODE_SIM><<<dim3(32, 32, 1), 256, 0, stream>>>(
        x_bf, x_bf, 1408, 1408, 1408, nullptr, 0, 0, norms, mask, 0, 0, 0);

    const int nBatches = 8 / BH;
    for (int bi = 0; bi < nBatches; ++bi) {
        // Wh = x @ W for BH heads
        gemm_bt<MODE_BF16><<<dim3(32, 8, BH), 256, 0, stream>>>(
            x_bf, Wt_bf + (long long)bi * BH * 1024 * 1408, 1408, 1408, 1408,
            Wh_b, 1024, 1024, nullptr, nullptr,
            0, 1024LL * 1408, 4096LL * 1024);
        head_f1f2<<<dim3(4096, BH), 256, 0, stream>>>(Wh_b, a_att, f12, bi * BH);
        attn_head<<<dim3(4096, BH), 256, 0, stream>>>(Wh_b, f12, mask, hout_b, bi * BH, BH);
        // out partial GEMM: split-K into BH chunks of 1024
        gemm_bt<MODE_F32><<<dim3(32, 1, BH), 256, 0, stream>>>(
            hout_b, WoutT + (long long)bi * BH * 1024, BH * 1024, 8192, 1024,
            parts + (long long)bi * BH * 4096 * 64, 64, 64, nullptr, nullptr,
            1024, 1024, 4096LL * 64);
    }

    out_reduce_f<<<4096, 64, 0, stream>>>(parts, a_out, Cout, f1o, f2o);
    attn_out<<<4096, 64, 0, stream>>>(Cout, f1o, f2o, mask, out);
}

// Round 2
// 371.900 us; speedup vs baseline: 1.4040x; 1.4040x over previous
//
#include <hip/hip_runtime.h>
#include <hip/hip_bf16.h>
#include <stdint.h>
#include <math.h>

// ---------------------------------------------------------------------------
// GATNet on MI355X.
// adj is only a mask (adj>0 <=> x_i.x_j >= 0.8*|x_i||x_j|); mask is ~identity
// for this data, so attention is a sparse bit-mask scan + online softmax.
// R1: added per-row 128-bit "summary" (which mask words are nonzero) so the
// attention kernels skip the 128-word serial scan (was 10 us/block latency).
// ---------------------------------------------------------------------------

typedef __bf16 bf16x8 __attribute__((ext_vector_type(8)));
typedef float  f32x4  __attribute__((ext_vector_type(4)));

#define AS1C(p) ((const __attribute__((address_space(1))) void*)(p))
#define AS3(p)  ((__attribute__((address_space(3))) void*)(p))

#define MODE_BF16 0
#define MODE_SIM  1
#define MODE_F32  2

__device__ __forceinline__ float bfbits2f(unsigned short u) {
    return __uint_as_float(((unsigned)u) << 16);
}
__device__ __forceinline__ unsigned short f2bfbits(float v) {
    __hip_bfloat16 b = __float2bfloat16(v);
    return *(unsigned short*)&b;
}

// C = A(M x K, lda) * B^T where B is (N x K, ldb), both bf16 row-major.
// 128x128 tile, BK=32, 256 threads (4 waves, 2x2 of 64x64), 16x16x32 MFMA.
template<int MODE>
__global__ __launch_bounds__(256, 2)
void gemm_bt(const __hip_bfloat16* __restrict__ A,
             const __hip_bfloat16* __restrict__ B,
             int lda, int ldb, int K,
             void* __restrict__ Cv, int ldc, int Nreal,
             const float* __restrict__ norms,
             unsigned* __restrict__ mask,
             unsigned* __restrict__ summary,
             long long zA, long long zB, long long zC)
{
    __shared__ __align__(16) __hip_bfloat16 As[128 * 32];
    __shared__ __align__(16) __hip_bfloat16 Bs[128 * 32];

    const int tid  = threadIdx.x;
    const int lane = tid & 63;
    const int wave = tid >> 6;
    const int m0   = blockIdx.x * 128;
    const int n0   = blockIdx.y * 128;
    const int z    = blockIdx.z;

    A += (long long)z * zA;
    B += (long long)z * zB;

    f32x4 acc[4][4];
#pragma unroll
    for (int i = 0; i < 4; ++i)
#pragma unroll
        for (int j = 0; j < 4; ++j)
#pragma unroll
            for (int k = 0; k < 4; ++k) acc[i][j][k] = 0.f;

    const int wm = wave >> 1, wn = wave & 1;
    const int q  = lane >> 4, ln = lane & 15;

    const int kIters = K >> 5;
    for (int kt = 0; kt < kIters; ++kt) {
        __syncthreads();
#pragma unroll
        for (int p = 0; p < 2; ++p) {
            const int t   = p * 256 + tid;
            const int row = t >> 2;
            const int kb  = (t & 3) ^ ((t >> 3) & 3);   // XOR swizzle slot
            const __hip_bfloat16* ga = A + (long long)(m0 + row) * lda + kt * 32 + kb * 8;
            const __hip_bfloat16* gb = B + (long long)(n0 + row) * ldb + kt * 32 + kb * 8;
            __hip_bfloat16* sa = As + (p * 256 + wave * 64) * 8;
            __hip_bfloat16* sb = Bs + (p * 256 + wave * 64) * 8;
            __builtin_amdgcn_global_load_lds(AS1C(ga), AS3(sa), 16, 0, 0);
            __builtin_amdgcn_global_load_lds(AS1C(gb), AS3(sb), 16, 0, 0);
        }
        __syncthreads();

        bf16x8 afr[4], bfr[4];
#pragma unroll
        for (int rg = 0; rg < 4; ++rg) {
            const int r = wm * 64 + rg * 16 + ln;
            const int s = q ^ ((r >> 1) & 3);
            afr[rg] = *(const bf16x8*)(As + r * 32 + s * 8);
        }
#pragma unroll
        for (int cg = 0; cg < 4; ++cg) {
            const int r = wn * 64 + cg * 16 + ln;
            const int s = q ^ ((r >> 1) & 3);
            bfr[cg] = *(const bf16x8*)(Bs + r * 32 + s * 8);
        }
#pragma unroll
        for (int rg = 0; rg < 4; ++rg)
#pragma unroll
            for (int cg = 0; cg < 4; ++cg)
                acc[rg][cg] = __builtin_amdgcn_mfma_f32_16x16x32_bf16(
                    afr[rg], bfr[cg], acc[rg][cg], 0, 0, 0);
    }

    // epilogue: C/D layout col=lane&15, row=quad*4+reg (m89/m91-verified)
#pragma unroll
    for (int rg = 0; rg < 4; ++rg) {
#pragma unroll
        for (int cg = 0; cg < 4; ++cg) {
#pragma unroll
            for (int i = 0; i < 4; ++i) {
                const int row = m0 + wm * 64 + rg * 16 + q * 4 + i;
                const int col = n0 + wn * 64 + cg * 16 + ln;
                const float v = acc[rg][cg][i];
                if (MODE == MODE_BF16) {
                    __hip_bfloat16* C = (__hip_bfloat16*)Cv + (long long)z * zC;
                    C[(long long)row * ldc + col] = __float2bfloat16(v);
                } else if (MODE == MODE_SIM) {
                    if (v >= 0.8f * norms[row] * norms[col]) {
                        atomicOr(&mask[row * 128 + (col >> 5)], 1u << (col & 31));
                        atomicOr(&summary[row * 4 + (col >> 10)], 1u << ((col >> 5) & 31));
                    }
                } else {
                    if (col < Nreal) {
                        float* C = (float*)Cv + (long long)z * zC;
                        C[(long long)row * ldc + col] = v;
                    }
                }
            }
        }
    }
}

// x (4096x1386 f32) -> x_bf (4096x1408 bf16, zero-pad) + row norms
__global__ void convert_x(const float* __restrict__ x,
                          __hip_bfloat16* __restrict__ xb,
                          float* __restrict__ norms)
{
    const int i = blockIdx.x, tid = threadIdx.x;
    float ss = 0.f;
    for (int c = tid; c < 1408; c += 256) {
        float v = (c < 1386) ? x[(long long)i * 1386 + c] : 0.f;
        xb[(long long)i * 1408 + c] = __float2bfloat16(v);
        ss += v * v;
    }
    for (int off = 32; off; off >>= 1) ss += __shfl_down(ss, off);
    __shared__ float red[4];
    if ((tid & 63) == 0) red[tid >> 6] = ss;
    __syncthreads();
    if (tid == 0) norms[i] = fmaxf(sqrtf(red[0] + red[1] + red[2] + red[3]), 1e-12f);
}

// src (K x N f32) -> dst (Npad x Kpad bf16) transposed, zero-pad; batched
__global__ void transpose_bf(const float* __restrict__ src,
                             __hip_bfloat16* __restrict__ dst,
                             int K, int N, int Kpad, int Npad,
                             long long sStride, long long dStride)
{
    __shared__ float ts[32][33];
    const int b  = blockIdx.z;
    const int k0 = blockIdx.x * 32;
    const int n0 = blockIdx.y * 32;
    const int tx = threadIdx.x, ty = threadIdx.y;
    const float* s = src + b * sStride;
    __hip_bfloat16* d = dst + b * dStride;
#pragma unroll
    for (int i = 0; i < 4; ++i) {
        const int k = k0 + ty + i * 8;
        const int n = n0 + tx;
        ts[ty + i * 8][tx] = (k < K && n < N) ? s[(long long)k * N + n] : 0.f;
    }
    __syncthreads();
#pragma unroll
    for (int i = 0; i < 4; ++i) {
        const int n  = n0 + ty + i * 8;
        const int kk = k0 + tx;
        if (n < Npad && kk < Kpad)
            d[(long long)n * Kpad + kk] = __float2bfloat16(ts[tx][ty + i * 8]);
    }
}

// f1/f2 per row per head from bf16 Wh
__global__ void head_f1f2(const __hip_bfloat16* __restrict__ Wh,
                          const float* __restrict__ a_att,
                          float2* __restrict__ f12, int head_base)
{
    const int i = blockIdx.x, hl = blockIdx.y, tid = threadIdx.x;
    const int h = head_base + hl;
    const __hip_bfloat16* w = Wh + ((long long)hl * 4096 + i) * 1024;
    const float* a1 = a_att + (long long)h * 2048;
    const float* a2 = a1 + 1024;
    float s1 = 0.f, s2 = 0.f;
#pragma unroll
    for (int qq = 0; qq < 4; ++qq) {
        const int c = tid + qq * 256;
        const float v = __bfloat162float(w[c]);
        s1 += v * a1[c];
        s2 += v * a2[c];
    }
    for (int off = 32; off; off >>= 1) { s1 += __shfl_down(s1, off); s2 += __shfl_down(s2, off); }
    __shared__ float r1[4], r2[4];
    if ((tid & 63) == 0) { r1[tid >> 6] = s1; r2[tid >> 6] = s2; }
    __syncthreads();
    if (tid == 0) {
        float2 o;
        o.x = r1[0] + r1[1] + r1[2] + r1[3];
        o.y = r2[0] + r2[1] + r2[2] + r2[3];
        f12[(long long)h * 4096 + i] = o;
    }
}

// masked online-softmax attention + ELU -> hout slice (bf16)
// summary-driven: only nonzero mask words are touched.
__global__ void attn_head(const __hip_bfloat16* __restrict__ Wh,
                          const float2* __restrict__ f12,
                          const unsigned* __restrict__ mask,
                          const unsigned* __restrict__ summary,
                          __hip_bfloat16* __restrict__ hout,
                          int head_base, int BH)
{
    const int i = blockIdx.x, hl = blockIdx.y, tid = threadIdx.x;
    const int h = head_base + hl;
    const float2* f = f12 + (long long)h * 4096;
    const float f1 = f[i].x;
    const unsigned* mrow = mask + (long long)i * 128;
    const __hip_bfloat16* WhH = Wh + (long long)hl * 4096 * 1024;
    const uint4 sm = *(const uint4*)(summary + (long long)i * 4);
    unsigned sw[4] = { sm.x, sm.y, sm.z, sm.w };

    float m = -INFINITY, l = 0.f;
    float a0 = 0.f, a1 = 0.f, a2 = 0.f, a3 = 0.f;
#pragma unroll
    for (int s = 0; s < 4; ++s) {
        unsigned sb = sw[s];
        while (sb) {
            const int w = s * 32 + __builtin_ctz(sb);
            sb &= sb - 1;
            unsigned bits = mrow[w];
            while (bits) {
                const int j = w * 32 + __builtin_ctz(bits);
                bits &= bits - 1;
                float e = f1 + f[j].y;
                e = e > 0.f ? e : 0.2f * e;           // leaky_relu 0.2
                float wgt;
                if (e > m) {
                    const float sc = __expf(m - e);   // 0 on first iter
                    l *= sc; a0 *= sc; a1 *= sc; a2 *= sc; a3 *= sc;
                    m = e; wgt = 1.f;
                } else {
                    wgt = __expf(e - m);
                }
                l += wgt;
                const ushort4 wv = *(const ushort4*)(WhH + (long long)j * 1024 + tid * 4);
                a0 += wgt * bfbits2f(wv.x);
                a1 += wgt * bfbits2f(wv.y);
                a2 += wgt * bfbits2f(wv.z);
                a3 += wgt * bfbits2f(wv.w);
            }
        }
    }
    const float inv = 1.f / l;
    float v;
    ushort4 o;
    v = a0 * inv; v = v > 0.f ? v : (__expf(v) - 1.f); o.x = f2bfbits(v);
    v = a1 * inv; v = v > 0.f ? v : (__expf(v) - 1.f); o.y = f2bfbits(v);
    v = a2 * inv; v = v > 0.f ? v : (__expf(v) - 1.f); o.z = f2bfbits(v);
    v = a3 * inv; v = v > 0.f ? v : (__expf(v) - 1.f); o.w = f2bfbits(v);
    *(ushort4*)(hout + (long long)i * (BH * 1024) + (long long)hl * 1024 + tid * 4) = o;
}

// sum 8 split-K parts -> Cout; fused f1o/f2o dot products (64 threads = 1 wave)
__global__ void out_reduce_f(const float* __restrict__ parts,
                             const float* __restrict__ a_out,
                             float* __restrict__ Cout,
                             float* __restrict__ f1o,
                             float* __restrict__ f2o)
{
    const int i = blockIdx.x, c = threadIdx.x;
    float v = 0.f;
#pragma unroll
    for (int z = 0; z < 8; ++z) v += parts[(long long)z * 4096 * 64 + (long long)i * 64 + c];
    Cout[(long long)i * 64 + c] = v;
    float s1 = v * a_out[c];
    float s2 = v * a_out[64 + c];
    for (int off = 32; off; off >>= 1) { s1 += __shfl_down(s1, off); s2 += __shfl_down(s2, off); }
    if (c == 0) { f1o[i] = s1; f2o[i] = s2; }
}

// final masked attention over Cout + tanh -> out (f32)
__global__ void attn_out(const float* __restrict__ Cout,
                         const float* __restrict__ f1o,
                         const float* __restrict__ f2o,
                         const unsigned* __restrict__ mask,
                         const unsigned* __restrict__ summary,
                         float* __restrict__ out)
{
    const int i = blockIdx.x, c = threadIdx.x;
    const float f1 = f1o[i];
    const unsigned* mrow = mask + (long long)i * 128;
    const uint4 sm = *(const uint4*)(summary + (long long)i * 4);
    unsigned sw[4] = { sm.x, sm.y, sm.z, sm.w };
    float m = -INFINITY, l = 0.f, acc = 0.f;
#pragma unroll
    for (int s = 0; s < 4; ++s) {
        unsigned sb = sw[s];
        while (sb) {
            const int w = s * 32 + __builtin_ctz(sb);
            sb &= sb - 1;
            unsigned bits = mrow[w];
            while (bits) {
                const int j = w * 32 + __builtin_ctz(bits);
                bits &= bits - 1;
                float e = f1 + f2o[j];
                e = e > 0.f ? e : 0.2f * e;
                float wgt;
                if (e > m) { const float sc = __expf(m - e); l *= sc; acc *= sc; m = e; wgt = 1.f; }
                else       { wgt = __expf(e - m); }
                l += wgt;
                acc += wgt * Cout[(long long)j * 64 + c];
            }
        }
    }
    out[(long long)i * 64 + c] = tanhf(acc / l);
}

extern "C" void kernel_launch(void* const* d_in, const int* in_sizes, int n_in,
                              void* d_out, int out_size, void* d_ws, size_t ws_size,
                              hipStream_t stream)
{
    (void)in_sizes; (void)n_in; (void)out_size;
    const float* x     = (const float*)d_in[0];
    const float* W_att = (const float*)d_in[1];
    const float* a_att = (const float*)d_in[2];
    const float* W_out = (const float*)d_in[3];
    const float* a_out = (const float*)d_in[4];
    float* out = (float*)d_out;

    char* ws = (char*)d_ws;
    size_t off = 0;
    auto alloc = [&](size_t bytes) -> void* {
        void* p = ws + off;
        off += (bytes + 255) & ~(size_t)255;
        return p;
    };

    __hip_bfloat16* x_bf  = (__hip_bfloat16*)alloc(4096LL * 1408 * 2);
    __hip_bfloat16* Wt_bf = (__hip_bfloat16*)alloc(8LL * 1024 * 1408 * 2);
    __hip_bfloat16* WoutT = (__hip_bfloat16*)alloc(128LL * 8192 * 2);
    float*          norms = (float*)alloc(4096 * 4);
    unsigned*       mask  = (unsigned*)alloc(4096LL * 128 * 4);
    unsigned*       summ  = (unsigned*)alloc(4096LL * 4 * 4);
    float2*         f12   = (float2*)alloc(8LL * 4096 * 8);
    float*          parts = (float*)alloc(8LL * 4096 * 64 * 4);
    float*          Cout  = (float*)alloc(4096LL * 64 * 4);
    float*          f1o   = (float*)alloc(4096 * 4);
    float*          f2o   = (float*)alloc(4096 * 4);
    const size_t statics = off;

    // pick head-batch size BH so Wh_batch + hout_batch fit in remaining ws
    int BH = 8;
    while (BH > 1 && statics + (size_t)BH * 2 * 8388608ULL + 512 > ws_size) BH >>= 1;
    if (statics + (size_t)BH * 2 * 8388608ULL + 512 > ws_size) return; // ws too small
    __hip_bfloat16* Wh_b   = (__hip_bfloat16*)alloc((size_t)BH * 4096 * 1024 * 2);
    __hip_bfloat16* hout_b = (__hip_bfloat16*)alloc((size_t)BH * 4096 * 1024 * 2);

    hipMemsetAsync(mask, 0, 4096LL * 128 * 4, stream);
    hipMemsetAsync(summ, 0, 4096LL * 4 * 4, stream);

    convert_x<<<4096, 256, 0, stream>>>(x, x_bf, norms);
    transpose_bf<<<dim3(44, 32, 8), dim3(32, 8), 0, stream>>>(
        W_att, Wt_bf, 1386, 1024, 1408, 1024, 1386LL * 1024, 1024LL * 1408);
    transpose_bf<<<dim3(256, 4, 1), dim3(32, 8), 0, stream>>>(
        W_out, WoutT, 8192, 64, 8192, 128, 0, 0);

    // adjacency mask: G = x_bf @ x_bf^T, bit set where G >= 0.8*n_i*n_j
    gemm_bt<MODE_SIM><<<dim3(32, 32, 1), 256, 0, stream>>>(
        x_bf, x_bf, 1408, 1408, 1408, nullptr, 0, 0, norms, mask, summ, 0, 0, 0);

    const int nBatches = 8 / BH;
    for (int bi = 0; bi < nBatches; ++bi) {
        // Wh = x @ W for BH heads
        gemm_bt<MODE_BF16><<<dim3(32, 8, BH), 256, 0, stream>>>(
            x_bf, Wt_bf + (long long)bi * BH * 1024 * 1408, 1408, 1408, 1408,
            Wh_b, 1024, 1024, nullptr, nullptr, nullptr,
            0, 1024LL * 1408, 4096LL * 1024);
        head_f1f2<<<dim3(4096, BH), 256, 0, stream>>>(Wh_b, a_att, f12, bi * BH);
        attn_head<<<dim3(4096, BH), 256, 0, stream>>>(Wh_b, f12, mask, summ, hout_b, bi * BH, BH);
        // out partial GEMM: split-K into BH chunks of 1024
        gemm_bt<MODE_F32><<<dim3(32, 1, BH), 256, 0, stream>>>(
            hout_b, WoutT + (long long)bi * BH * 1024, BH * 1024, 8192, 1024,
            parts + (long long)bi * BH * 4096 * 64, 64, 64, nullptr, nullptr, nullptr,
            1024, 1024, 4096LL * 64);
    }

    out_reduce_f<<<4096, 64, 0, stream>>>(parts, a_out, Cout, f1o, f2o);
    attn_out<<<4096, 64, 0, stream>>>(Cout, f1o, f2o, mask, summ, out);
}

// Round 3
// 349.065 us; speedup vs baseline: 1.4958x; 1.0654x over previous
//
#include <hip/hip_runtime.h>
#include <hip/hip_bf16.h>
#include <stdint.h>
#include <math.h>

// ---------------------------------------------------------------------------
// GATNet on MI355X.
// adj is only a mask (adj>0 <=> x_i.x_j >= 0.8*|x_i||x_j|); mask is ~identity
// for this data, so attention is a sparse bit-mask scan + online softmax.
// R1: per-row 128-bit summary bitmap -> attention skips the 128-word scan.
// R2: SIM gemm upper-triangle only (exact: bf16 dot is commutative);
//     f1/f2 fused into Wh-gemm epilogue; out-gemm split-K x2;
//     attention kernels wave-per-row with 16B loads.
// ---------------------------------------------------------------------------

typedef __bf16 bf16x8 __attribute__((ext_vector_type(8)));
typedef float  f32x4  __attribute__((ext_vector_type(4)));
typedef unsigned short ushort8 __attribute__((ext_vector_type(8)));

#define AS1C(p) ((const __attribute__((address_space(1))) void*)(p))
#define AS3(p)  ((__attribute__((address_space(3))) void*)(p))

#define MODE_BF16 0
#define MODE_SIM  1
#define MODE_F32  2

__device__ __forceinline__ float bfbits2f(unsigned short u) {
    return __uint_as_float(((unsigned)u) << 16);
}
__device__ __forceinline__ unsigned short f2bfbits(float v) {
    __hip_bfloat16 b = __float2bfloat16(v);
    return *(unsigned short*)&b;
}

// C = A(M x K, lda) * B^T where B is (N x K, ldb), both bf16 row-major.
// 128x128 tile, BK=32, 256 threads (4 waves, 2x2 of 64x64), 16x16x32 MFMA.
// MODE_SIM: grid is linearized upper triangle (bx<=by), writes mask bits both ways.
// MODE_BF16: epilogue also accumulates f1=Wh.a1, f2=Wh.a2 via atomics.
template<int MODE>
__global__ __launch_bounds__(256, 2)
void gemm_bt(const __hip_bfloat16* __restrict__ A,
             const __hip_bfloat16* __restrict__ B,
             int lda, int ldb, int K,
             void* __restrict__ Cv, int ldc, int Nreal,
             const float* __restrict__ norms,
             unsigned* __restrict__ mask,
             unsigned* __restrict__ summary,
             const float* __restrict__ a_att,
             float2* __restrict__ f12,
             int head_base,
             long long zA, long long zB, long long zC)
{
    __shared__ __align__(16) __hip_bfloat16 As[128 * 32];
    __shared__ __align__(16) __hip_bfloat16 Bs[128 * 32];

    const int tid  = threadIdx.x;
    const int lane = tid & 63;
    const int wave = tid >> 6;
    const int z    = blockIdx.z;

    int bx, by;
    if (MODE == MODE_SIM) {
        const int id = blockIdx.x;                 // 0..527 upper triangle
        int t = (int)((sqrtf(8.f * id + 1.f) - 1.f) * 0.5f);
        while (t * (t + 1) / 2 > id) --t;
        while ((t + 1) * (t + 2) / 2 <= id) ++t;
        by = t; bx = id - t * (t + 1) / 2;         // bx <= by
    } else {
        bx = blockIdx.x; by = blockIdx.y;
    }
    const int m0 = bx * 128;
    const int n0 = by * 128;

    A += (long long)z * zA;
    B += (long long)z * zB;

    f32x4 acc[4][4];
#pragma unroll
    for (int i = 0; i < 4; ++i)
#pragma unroll
        for (int j = 0; j < 4; ++j)
#pragma unroll
            for (int k = 0; k < 4; ++k) acc[i][j][k] = 0.f;

    const int wm = wave >> 1, wn = wave & 1;
    const int q  = lane >> 4, ln = lane & 15;

    const int kIters = K >> 5;
    for (int kt = 0; kt < kIters; ++kt) {
        __syncthreads();
#pragma unroll
        for (int p = 0; p < 2; ++p) {
            const int t   = p * 256 + tid;
            const int row = t >> 2;
            const int kb  = (t & 3) ^ ((t >> 3) & 3);   // XOR swizzle slot
            const __hip_bfloat16* ga = A + (long long)(m0 + row) * lda + kt * 32 + kb * 8;
            const __hip_bfloat16* gb = B + (long long)(n0 + row) * ldb + kt * 32 + kb * 8;
            __hip_bfloat16* sa = As + (p * 256 + wave * 64) * 8;
            __hip_bfloat16* sb = Bs + (p * 256 + wave * 64) * 8;
            __builtin_amdgcn_global_load_lds(AS1C(ga), AS3(sa), 16, 0, 0);
            __builtin_amdgcn_global_load_lds(AS1C(gb), AS3(sb), 16, 0, 0);
        }
        __syncthreads();

        bf16x8 afr[4], bfr[4];
#pragma unroll
        for (int rg = 0; rg < 4; ++rg) {
            const int r = wm * 64 + rg * 16 + ln;
            const int s = q ^ ((r >> 1) & 3);
            afr[rg] = *(const bf16x8*)(As + r * 32 + s * 8);
        }
#pragma unroll
        for (int cg = 0; cg < 4; ++cg) {
            const int r = wn * 64 + cg * 16 + ln;
            const int s = q ^ ((r >> 1) & 3);
            bfr[cg] = *(const bf16x8*)(Bs + r * 32 + s * 8);
        }
#pragma unroll
        for (int rg = 0; rg < 4; ++rg)
#pragma unroll
            for (int cg = 0; cg < 4; ++cg)
                acc[rg][cg] = __builtin_amdgcn_mfma_f32_16x16x32_bf16(
                    afr[rg], bfr[cg], acc[rg][cg], 0, 0, 0);
    }

    // epilogue: C/D layout col=lane&15, row=quad*4+reg (m89/m91-verified)
    const float* a1 = nullptr; const float* a2 = nullptr;
    if (MODE == MODE_BF16) {
        a1 = a_att + (long long)(head_base + z) * 2048;
        a2 = a1 + 1024;
    }
#pragma unroll
    for (int rg = 0; rg < 4; ++rg) {
#pragma unroll
        for (int i = 0; i < 4; ++i) {
            const int row = m0 + wm * 64 + rg * 16 + q * 4 + i;
            float s1 = 0.f, s2 = 0.f;
#pragma unroll
            for (int cg = 0; cg < 4; ++cg) {
                const int col = n0 + wn * 64 + cg * 16 + ln;
                const float v = acc[rg][cg][i];
                if (MODE == MODE_BF16) {
                    __hip_bfloat16* C = (__hip_bfloat16*)Cv + (long long)z * zC;
                    C[(long long)row * ldc + col] = __float2bfloat16(v);
                    s1 += v * a1[col];
                    s2 += v * a2[col];
                } else if (MODE == MODE_SIM) {
                    if (v >= 0.8f * norms[row] * norms[col]) {
                        atomicOr(&mask[row * 128 + (col >> 5)], 1u << (col & 31));
                        atomicOr(&summary[row * 4 + (col >> 10)], 1u << ((col >> 5) & 31));
                        atomicOr(&mask[col * 128 + (row >> 5)], 1u << (row & 31));
                        atomicOr(&summary[col * 4 + (row >> 10)], 1u << ((row >> 5) & 31));
                    }
                } else {
                    if (col < Nreal) {
                        float* C = (float*)Cv + (long long)z * zC;
                        C[(long long)row * ldc + col] = v;
                    }
                }
            }
            if (MODE == MODE_BF16) {
                // reduce over the 16 lanes (ln) of this q-group
#pragma unroll
                for (int off = 8; off; off >>= 1) {
                    s1 += __shfl_down(s1, off, 16);
                    s2 += __shfl_down(s2, off, 16);
                }
                if (ln == 0) {
                    float2* fp = f12 + (long long)(head_base + z) * 4096 + row;
                    atomicAdd(&fp->x, s1);
                    atomicAdd(&fp->y, s2);
                }
            }
        }
    }
}

// x (4096x1386 f32) -> x_bf (4096x1408 bf16, zero-pad) + row norms
__global__ void convert_x(const float* __restrict__ x,
                          __hip_bfloat16* __restrict__ xb,
                          float* __restrict__ norms)
{
    const int i = blockIdx.x, tid = threadIdx.x;
    float ss = 0.f;
    for (int c = tid; c < 1408; c += 256) {
        float v = (c < 1386) ? x[(long long)i * 1386 + c] : 0.f;
        xb[(long long)i * 1408 + c] = __float2bfloat16(v);
        ss += v * v;
    }
    for (int off = 32; off; off >>= 1) ss += __shfl_down(ss, off);
    __shared__ float red[4];
    if ((tid & 63) == 0) red[tid >> 6] = ss;
    __syncthreads();
    if (tid == 0) norms[i] = fmaxf(sqrtf(red[0] + red[1] + red[2] + red[3]), 1e-12f);
}

// src (K x N f32) -> dst (Npad x Kpad bf16) transposed, zero-pad; batched
__global__ void transpose_bf(const float* __restrict__ src,
                             __hip_bfloat16* __restrict__ dst,
                             int K, int N, int Kpad, int Npad,
                             long long sStride, long long dStride)
{
    __shared__ float ts[32][33];
    const int b  = blockIdx.z;
    const int k0 = blockIdx.x * 32;
    const int n0 = blockIdx.y * 32;
    const int tx = threadIdx.x, ty = threadIdx.y;
    const float* s = src + b * sStride;
    __hip_bfloat16* d = dst + b * dStride;
#pragma unroll
    for (int i = 0; i < 4; ++i) {
        const int k = k0 + ty + i * 8;
        const int n = n0 + tx;
        ts[ty + i * 8][tx] = (k < K && n < N) ? s[(long long)k * N + n] : 0.f;
    }
    __syncthreads();
#pragma unroll
    for (int i = 0; i < 4; ++i) {
        const int n  = n0 + ty + i * 8;
        const int kk = k0 + tx;
        if (n < Npad && kk < Kpad)
            d[(long long)n * Kpad + kk] = __float2bfloat16(ts[tx][ty + i * 8]);
    }
}

// masked online-softmax attention + ELU -> hout slice (bf16).
// one wave per (row, head); lane covers 16 consecutive cols (2x16B loads).
__global__ __launch_bounds__(256)
void attn_head(const __hip_bfloat16* __restrict__ Wh,
               const float2* __restrict__ f12,
               const unsigned* __restrict__ mask,
               const unsigned* __restrict__ summary,
               __hip_bfloat16* __restrict__ hout,
               int head_base, int BH)
{
    const int wv   = threadIdx.x >> 6;
    const int lane = threadIdx.x & 63;
    const int i    = blockIdx.x * 4 + wv;
    const int hl   = blockIdx.y;
    const int h    = head_base + hl;
    const float2* f = f12 + (long long)h * 4096;
    const float f1 = f[i].x;
    const unsigned* mrow = mask + (long long)i * 128;
    const __hip_bfloat16* WhH = Wh + (long long)hl * 4096 * 1024;
    const uint4 sm = *(const uint4*)(summary + (long long)i * 4);
    unsigned sw[4] = { sm.x, sm.y, sm.z, sm.w };
    const int cbase = lane * 16;

    float m = -INFINITY, l = 0.f;
    float acc[16];
#pragma unroll
    for (int k = 0; k < 16; ++k) acc[k] = 0.f;

#pragma unroll
    for (int s = 0; s < 4; ++s) {
        unsigned sb = sw[s];
        while (sb) {
            const int w = s * 32 + __builtin_ctz(sb);
            sb &= sb - 1;
            unsigned bits = mrow[w];
            while (bits) {
                const int j = w * 32 + __builtin_ctz(bits);
                bits &= bits - 1;
                float e = f1 + f[j].y;
                e = e > 0.f ? e : 0.2f * e;           // leaky_relu 0.2
                float wgt;
                if (e > m) {
                    const float sc = __expf(m - e);   // 0 on first iter
                    l *= sc;
#pragma unroll
                    for (int k = 0; k < 16; ++k) acc[k] *= sc;
                    m = e; wgt = 1.f;
                } else {
                    wgt = __expf(e - m);
                }
                l += wgt;
                const ushort8* p = (const ushort8*)(WhH + (long long)j * 1024 + cbase);
                const ushort8 w0 = p[0], w1 = p[1];
#pragma unroll
                for (int k = 0; k < 8; ++k) acc[k]     += wgt * bfbits2f(w0[k]);
#pragma unroll
                for (int k = 0; k < 8; ++k) acc[k + 8] += wgt * bfbits2f(w1[k]);
            }
        }
    }
    const float inv = 1.f / l;
    ushort8 o0, o1;
#pragma unroll
    for (int k = 0; k < 8; ++k) {
        float v = acc[k] * inv;     v = v > 0.f ? v : (__expf(v) - 1.f); o0[k] = f2bfbits(v);
        float u = acc[k + 8] * inv; u = u > 0.f ? u : (__expf(u) - 1.f); o1[k] = f2bfbits(u);
    }
    ushort8* op = (ushort8*)(hout + (long long)i * (BH * 1024) + (long long)hl * 1024 + cbase);
    op[0] = o0; op[1] = o1;
}

// sum 16 split-K parts -> Cout; fused f1o/f2o dot products (64 threads = 1 wave)
__global__ void out_reduce_f(const float* __restrict__ parts,
                             const float* __restrict__ a_out,
                             float* __restrict__ Cout,
                             float* __restrict__ f1o,
                             float* __restrict__ f2o)
{
    const int i = blockIdx.x, c = threadIdx.x;
    float v = 0.f;
#pragma unroll
    for (int z = 0; z < 16; ++z) v += parts[(long long)z * 4096 * 64 + (long long)i * 64 + c];
    Cout[(long long)i * 64 + c] = v;
    float s1 = v * a_out[c];
    float s2 = v * a_out[64 + c];
    for (int off = 32; off; off >>= 1) { s1 += __shfl_down(s1, off); s2 += __shfl_down(s2, off); }
    if (c == 0) { f1o[i] = s1; f2o[i] = s2; }
}

// final masked attention over Cout + tanh -> out (f32); one wave per row
__global__ __launch_bounds__(256)
void attn_out(const float* __restrict__ Cout,
              const float* __restrict__ f1o,
              const float* __restrict__ f2o,
              const unsigned* __restrict__ mask,
              const unsigned* __restrict__ summary,
              float* __restrict__ out)
{
    const int wv = threadIdx.x >> 6;
    const int c  = threadIdx.x & 63;
    const int i  = blockIdx.x * 4 + wv;
    const float f1 = f1o[i];
    const unsigned* mrow = mask + (long long)i * 128;
    const uint4 sm = *(const uint4*)(summary + (long long)i * 4);
    unsigned sw[4] = { sm.x, sm.y, sm.z, sm.w };
    float m = -INFINITY, l = 0.f, acc = 0.f;
#pragma unroll
    for (int s = 0; s < 4; ++s) {
        unsigned sb = sw[s];
        while (sb) {
            const int w = s * 32 + __builtin_ctz(sb);
            sb &= sb - 1;
            unsigned bits = mrow[w];
            while (bits) {
                const int j = w * 32 + __builtin_ctz(bits);
                bits &= bits - 1;
                float e = f1 + f2o[j];
                e = e > 0.f ? e : 0.2f * e;
                float wgt;
                if (e > m) { const float sc = __expf(m - e); l *= sc; acc *= sc; m = e; wgt = 1.f; }
                else       { wgt = __expf(e - m); }
                l += wgt;
                acc += wgt * Cout[(long long)j * 64 + c];
            }
        }
    }
    out[(long long)i * 64 + c] = tanhf(acc / l);
}

extern "C" void kernel_launch(void* const* d_in, const int* in_sizes, int n_in,
                              void* d_out, int out_size, void* d_ws, size_t ws_size,
                              hipStream_t stream)
{
    (void)in_sizes; (void)n_in; (void)out_size;
    const float* x     = (const float*)d_in[0];
    const float* W_att = (const float*)d_in[1];
    const float* a_att = (const float*)d_in[2];
    const float* W_out = (const float*)d_in[3];
    const float* a_out = (const float*)d_in[4];
    float* out = (float*)d_out;

    char* ws = (char*)d_ws;
    size_t off = 0;
    auto alloc = [&](size_t bytes) -> void* {
        void* p = ws + off;
        off += (bytes + 255) & ~(size_t)255;
        return p;
    };

    __hip_bfloat16* x_bf  = (__hip_bfloat16*)alloc(4096LL * 1408 * 2);
    __hip_bfloat16* Wt_bf = (__hip_bfloat16*)alloc(8LL * 1024 * 1408 * 2);
    __hip_bfloat16* WoutT = (__hip_bfloat16*)alloc(128LL * 8192 * 2);
    float*          norms = (float*)alloc(4096 * 4);
    unsigned*       mask  = (unsigned*)alloc(4096LL * 128 * 4);
    unsigned*       summ  = (unsigned*)alloc(4096LL * 4 * 4);
    float2*         f12   = (float2*)alloc(8LL * 4096 * 8);
    float*          parts = (float*)alloc(16LL * 4096 * 64 * 4);
    float*          Cout  = (float*)alloc(4096LL * 64 * 4);
    float*          f1o   = (float*)alloc(4096 * 4);
    float*          f2o   = (float*)alloc(4096 * 4);
    const size_t statics = off;

    // pick head-batch size BH so Wh_batch + hout_batch fit in remaining ws
    int BH = 8;
    while (BH > 1 && statics + (size_t)BH * 2 * 8388608ULL + 512 > ws_size) BH >>= 1;
    if (statics + (size_t)BH * 2 * 8388608ULL + 512 > ws_size) return; // ws too small
    __hip_bfloat16* Wh_b   = (__hip_bfloat16*)alloc((size_t)BH * 4096 * 1024 * 2);
    __hip_bfloat16* hout_b = (__hip_bfloat16*)alloc((size_t)BH * 4096 * 1024 * 2);

    hipMemsetAsync(mask, 0, 4096LL * 128 * 4, stream);
    hipMemsetAsync(summ, 0, 4096LL * 4 * 4, stream);
    hipMemsetAsync(f12,  0, 8LL * 4096 * 8, stream);

    convert_x<<<4096, 256, 0, stream>>>(x, x_bf, norms);
    transpose_bf<<<dim3(44, 32, 8), dim3(32, 8), 0, stream>>>(
        W_att, Wt_bf, 1386, 1024, 1408, 1024, 1386LL * 1024, 1024LL * 1408);
    transpose_bf<<<dim3(256, 4, 1), dim3(32, 8), 0, stream>>>(
        W_out, WoutT, 8192, 64, 8192, 128, 0, 0);

    // adjacency mask: G = x_bf @ x_bf^T, upper triangle only (528 blocks)
    gemm_bt<MODE_SIM><<<dim3(528, 1, 1), 256, 0, stream>>>(
        x_bf, x_bf, 1408, 1408, 1408, nullptr, 0, 0, norms, mask, summ,
        nullptr, nullptr, 0, 0, 0, 0);

    const int nBatches = 8 / BH;
    for (int bi = 0; bi < nBatches; ++bi) {
        // Wh = x @ W for BH heads; epilogue accumulates f1/f2
        gemm_bt<MODE_BF16><<<dim3(32, 8, BH), 256, 0, stream>>>(
            x_bf, Wt_bf + (long long)bi * BH * 1024 * 1408, 1408, 1408, 1408,
            Wh_b, 1024, 1024, nullptr, nullptr, nullptr,
            a_att, f12, bi * BH,
            0, 1024LL * 1408, 4096LL * 1024);
        attn_head<<<dim3(1024, BH), 256, 0, stream>>>(Wh_b, f12, mask, summ, hout_b, bi * BH, BH);
        // out partial GEMM: split-K into 2*BH chunks of 512
        gemm_bt<MODE_F32><<<dim3(32, 1, 2 * BH), 256, 0, stream>>>(
            hout_b, WoutT + (long long)bi * BH * 1024, BH * 1024, 8192, 512,
            parts + (long long)bi * 2 * BH * 4096 * 64, 64, 64,
            nullptr, nullptr, nullptr, nullptr, nullptr, 0,
            512, 512, 4096LL * 64);
    }

    out_reduce_f<<<4096, 64, 0, stream>>>(parts, a_out, Cout, f1o, f2o);
    attn_out<<<1024, 256, 0, stream>>>(Cout, f1o, f2o, mask, summ, out);
}

// Round 4
// 326.269 us; speedup vs baseline: 1.6003x; 1.0699x over previous
//
#include <hip/hip_runtime.h>
#include <hip/hip_bf16.h>
#include <stdint.h>
#include <math.h>

// ---------------------------------------------------------------------------
// GATNet on MI355X.
// adj is only a mask (adj>0 <=> x_i.x_j >= 0.8*|x_i||x_j|); mask is ~identity
// for this data, so attention is a sparse bit-mask scan + online softmax.
// R1: per-row 128-bit summary bitmap -> attention skips the 128-word scan.
// R2: SIM upper-triangle only; split-K out-gemm; wave-per-row attention.
// R3(=this): f12 = x @ (W @ a) in fp32 (removes Wh re-read AND the atomic
//   epilogue that thrashed 33 MB of HBM writebacks); one prestage kernel;
//   one mega-GEMM dispatch (SIM + Wh + f12x) to overlap tails; 7 dispatches.
// ---------------------------------------------------------------------------

typedef __bf16 bf16x8 __attribute__((ext_vector_type(8)));
typedef float  f32x4  __attribute__((ext_vector_type(4)));
typedef unsigned short ushort8 __attribute__((ext_vector_type(8)));

#define AS1C(p) ((const __attribute__((address_space(1))) void*)(p))
#define AS3(p)  ((__attribute__((address_space(3))) void*)(p))

#define MODE_BF16 0
#define MODE_SIM  1
#define MODE_F32  2

__device__ __forceinline__ float bfbits2f(unsigned short u) {
    return __uint_as_float(((unsigned)u) << 16);
}
__device__ __forceinline__ unsigned short f2bfbits(float v) {
    __hip_bfloat16 b = __float2bfloat16(v);
    return *(unsigned short*)&b;
}

// C = A(M x K, lda) * B^T, B is (N x K, ldb), both bf16 row-major.
// 128x128 tile, BK=32, 256 threads (4 waves, 2x2 of 64x64), 16x16x32 MFMA.
template<int MODE>
__device__ __forceinline__ void gemm_body(
    __hip_bfloat16* __restrict__ As, __hip_bfloat16* __restrict__ Bs,
    int bx, int by,
    const __hip_bfloat16* __restrict__ A,
    const __hip_bfloat16* __restrict__ B,
    int lda, int ldb, int K,
    void* __restrict__ Cv, int ldc, int Nreal,
    const float* __restrict__ norms,
    unsigned* __restrict__ mask,
    unsigned* __restrict__ summary)
{
    const int tid  = threadIdx.x;
    const int lane = tid & 63;
    const int wave = tid >> 6;
    const int m0   = bx * 128;
    const int n0   = by * 128;

    f32x4 acc[4][4];
#pragma unroll
    for (int i = 0; i < 4; ++i)
#pragma unroll
        for (int j = 0; j < 4; ++j)
#pragma unroll
            for (int k = 0; k < 4; ++k) acc[i][j][k] = 0.f;

    const int wm = wave >> 1, wn = wave & 1;
    const int q  = lane >> 4, ln = lane & 15;

    const int kIters = K >> 5;
    for (int kt = 0; kt < kIters; ++kt) {
        __syncthreads();
#pragma unroll
        for (int p = 0; p < 2; ++p) {
            const int t   = p * 256 + tid;
            const int row = t >> 2;
            const int kb  = (t & 3) ^ ((t >> 3) & 3);   // XOR swizzle slot
            const __hip_bfloat16* ga = A + (long long)(m0 + row) * lda + kt * 32 + kb * 8;
            const __hip_bfloat16* gb = B + (long long)(n0 + row) * ldb + kt * 32 + kb * 8;
            __hip_bfloat16* sa = As + (p * 256 + wave * 64) * 8;
            __hip_bfloat16* sb = Bs + (p * 256 + wave * 64) * 8;
            __builtin_amdgcn_global_load_lds(AS1C(ga), AS3(sa), 16, 0, 0);
            __builtin_amdgcn_global_load_lds(AS1C(gb), AS3(sb), 16, 0, 0);
        }
        __syncthreads();

        bf16x8 afr[4], bfr[4];
#pragma unroll
        for (int rg = 0; rg < 4; ++rg) {
            const int r = wm * 64 + rg * 16 + ln;
            const int s = q ^ ((r >> 1) & 3);
            afr[rg] = *(const bf16x8*)(As + r * 32 + s * 8);
        }
#pragma unroll
        for (int cg = 0; cg < 4; ++cg) {
            const int r = wn * 64 + cg * 16 + ln;
            const int s = q ^ ((r >> 1) & 3);
            bfr[cg] = *(const bf16x8*)(Bs + r * 32 + s * 8);
        }
#pragma unroll
        for (int rg = 0; rg < 4; ++rg)
#pragma unroll
            for (int cg = 0; cg < 4; ++cg)
                acc[rg][cg] = __builtin_amdgcn_mfma_f32_16x16x32_bf16(
                    afr[rg], bfr[cg], acc[rg][cg], 0, 0, 0);
    }

    // epilogue: C/D layout col=lane&15, row=quad*4+reg (m89/m91-verified)
#pragma unroll
    for (int rg = 0; rg < 4; ++rg) {
#pragma unroll
        for (int cg = 0; cg < 4; ++cg) {
#pragma unroll
            for (int i = 0; i < 4; ++i) {
                const int row = m0 + wm * 64 + rg * 16 + q * 4 + i;
                const int col = n0 + wn * 64 + cg * 16 + ln;
                const float v = acc[rg][cg][i];
                if (MODE == MODE_BF16) {
                    __hip_bfloat16* C = (__hip_bfloat16*)Cv;
                    C[(long long)row * ldc + col] = __float2bfloat16(v);
                } else if (MODE == MODE_SIM) {
                    if (v >= 0.8f * norms[row] * norms[col]) {
                        atomicOr(&mask[row * 128 + (col >> 5)], 1u << (col & 31));
                        atomicOr(&summary[row * 4 + (col >> 10)], 1u << ((col >> 5) & 31));
                        atomicOr(&mask[col * 128 + (row >> 5)], 1u << (row & 31));
                        atomicOr(&summary[col * 4 + (row >> 10)], 1u << ((row >> 5) & 31));
                    }
                } else {
                    if (col < Nreal) {
                        float* C = (float*)Cv;
                        C[(long long)row * ldc + col] = v;
                    }
                }
            }
        }
    }
}

// ---------------------------------------------------------------------------
// prestage: one dispatch, 256-thread blocks, linearized ranges:
//   [0,4096)            convert x row -> x_bf (pad 1408) + norm
//   [4096,15360)        transpose W_att (f32 (8,1386,1024) -> bf16 (8,1024,1408))
//   [15360,16384)       transpose W_out (f32 (8192,64) -> bf16 (128,8192))
//   [16384,19200)       wa[h][s][c] = sum_j W_att[h][c][j] * a_att[h][s*1024+j]
// ---------------------------------------------------------------------------
__global__ __launch_bounds__(256)
void prestage(const float* __restrict__ x,
              const float* __restrict__ W_att,
              const float* __restrict__ W_out,
              const float* __restrict__ a_att,
              __hip_bfloat16* __restrict__ x_bf,
              float* __restrict__ norms,
              __hip_bfloat16* __restrict__ Wt_bf,
              __hip_bfloat16* __restrict__ WoutT,
              float* __restrict__ wa)
{
    __shared__ float ts[32][33];
    __shared__ float red[4];
    const int id  = blockIdx.x;
    const int tid = threadIdx.x;

    if (id < 4096) {
        // ---- convert_x + norm ----
        const int i = id;
        float ss = 0.f;
        for (int c = tid; c < 1408; c += 256) {
            float v = (c < 1386) ? x[(long long)i * 1386 + c] : 0.f;
            x_bf[(long long)i * 1408 + c] = __float2bfloat16(v);
            ss += v * v;
        }
        for (int off = 32; off; off >>= 1) ss += __shfl_down(ss, off);
        if ((tid & 63) == 0) red[tid >> 6] = ss;
        __syncthreads();
        if (tid == 0) norms[i] = fmaxf(sqrtf(red[0] + red[1] + red[2] + red[3]), 1e-12f);
        return;
    }
    if (id < 16384) {
        // ---- 32x32 transpose f32 -> bf16 ----
        const float* s; __hip_bfloat16* d;
        int K, N, Kpad, Npad, k0, n0;
        if (id < 15360) {
            const int b = id - 4096;                 // 8 heads x 44 x 32
            const int h = b / 1408, r = b % 1408;
            const int kx = r % 44, ny = r / 44;
            s = W_att + (long long)h * 1386 * 1024;
            d = Wt_bf + (long long)h * 1024 * 1408;
            K = 1386; N = 1024; Kpad = 1408; Npad = 1024;
            k0 = kx * 32; n0 = ny * 32;
        } else {
            const int r = id - 15360;                // 256 x 4
            s = W_out; d = WoutT;
            K = 8192; N = 64; Kpad = 8192; Npad = 128;
            k0 = (r & 255) * 32; n0 = (r >> 8) * 32;
        }
        const int tx = tid & 31, ty = tid >> 5;
#pragma unroll
        for (int i = 0; i < 4; ++i) {
            const int k = k0 + ty + i * 8;
            const int n = n0 + tx;
            ts[ty + i * 8][tx] = (k < K && n < N) ? s[(long long)k * N + n] : 0.f;
        }
        __syncthreads();
#pragma unroll
        for (int i = 0; i < 4; ++i) {
            const int n  = n0 + ty + i * 8;
            const int kk = k0 + tx;
            if (n < Npad && kk < Kpad)
                d[(long long)n * Kpad + kk] = __float2bfloat16(ts[tx][ty + i * 8]);
        }
        return;
    }
    // ---- wa: wave per (h, c); 4 c per block ----
    {
        const int b = id - 16384;                    // 8 heads x 352
        const int h = b / 352, r = b % 352;
        const int wave = tid >> 6, lane = tid & 63;
        const int c = r * 4 + wave;                  // 0..1407
        float s1 = 0.f, s2 = 0.f;
        if (c < 1386) {
            const float* wr = W_att + ((long long)h * 1386 + c) * 1024;
            const float* a1 = a_att + (long long)h * 2048;
            const float* a2 = a1 + 1024;
#pragma unroll
            for (int t = 0; t < 16; ++t) {
                const int j = lane + t * 64;
                const float w = wr[j];
                s1 += w * a1[j];
                s2 += w * a2[j];
            }
        }
        for (int off = 32; off; off >>= 1) { s1 += __shfl_down(s1, off); s2 += __shfl_down(s2, off); }
        if (lane == 0) {
            wa[(h * 2 + 0) * 1408 + c] = s1;
            wa[(h * 2 + 1) * 1408 + c] = s2;
        }
    }
}

// ---------------------------------------------------------------------------
// mega GEMM: [0,528) SIM upper-triangle; [528,2576) Wh (8 heads);
//            [2576,3600) f12 = x @ wa (wave per row, fp32)
// ---------------------------------------------------------------------------
__global__ __launch_bounds__(256, 2)
void mega_gemm(const __hip_bfloat16* __restrict__ x_bf,
               const __hip_bfloat16* __restrict__ Wt_bf,
               __hip_bfloat16* __restrict__ Wh,
               const float* __restrict__ norms,
               unsigned* __restrict__ mask,
               unsigned* __restrict__ summ,
               const float* __restrict__ x,
               const float* __restrict__ wa,
               float2* __restrict__ f12)
{
    __shared__ __align__(16) __hip_bfloat16 As[128 * 32];
    __shared__ __align__(16) __hip_bfloat16 Bs[128 * 32];
    const int id = blockIdx.x;

    if (id < 528) {
        int t = (int)((sqrtf(8.f * id + 1.f) - 1.f) * 0.5f);
        while (t * (t + 1) / 2 > id) --t;
        while ((t + 1) * (t + 2) / 2 <= id) ++t;
        const int by = t, bx = id - t * (t + 1) / 2;   // bx <= by
        gemm_body<MODE_SIM>(As, Bs, bx, by, x_bf, x_bf, 1408, 1408, 1408,
                            nullptr, 0, 0, norms, mask, summ);
        return;
    }
    if (id < 2576) {
        const int b  = id - 528;
        const int z  = b >> 8;          // head
        const int r  = b & 255;
        const int bx = r & 31, by = r >> 5;
        gemm_body<MODE_BF16>(As, Bs, bx, by,
                             x_bf, Wt_bf + (long long)z * 1024 * 1408,
                             1408, 1408, 1408,
                             Wh + (long long)z * 4096 * 1024, 1024, 1024,
                             nullptr, nullptr, nullptr);
        return;
    }
    // ---- f12x: wave per row ----
    {
        const int b    = id - 2576;
        const int wave = threadIdx.x >> 6, lane = threadIdx.x & 63;
        const int i    = b * 4 + wave;
        float s[16];
#pragma unroll
        for (int j = 0; j < 16; ++j) s[j] = 0.f;
        const float* xr = x + (long long)i * 1386;
        for (int c = lane; c < 1386; c += 64) {
            const float v = xr[c];
#pragma unroll
            for (int j = 0; j < 16; ++j) s[j] += v * wa[j * 1408 + c];
        }
#pragma unroll
        for (int j = 0; j < 16; ++j)
            for (int off = 32; off; off >>= 1) s[j] += __shfl_down(s[j], off);
        if (lane == 0) {
#pragma unroll
            for (int h = 0; h < 8; ++h)
                f12[(long long)h * 4096 + i] = make_float2(s[h * 2], s[h * 2 + 1]);
        }
    }
}

// out partial GEMM wrapper: split-K (16 chunks of 512)
__global__ __launch_bounds__(256, 2)
void out_gemm(const __hip_bfloat16* __restrict__ hout,
              const __hip_bfloat16* __restrict__ WoutT,
              float* __restrict__ parts)
{
    __shared__ __align__(16) __hip_bfloat16 As[128 * 32];
    __shared__ __align__(16) __hip_bfloat16 Bs[128 * 32];
    const int z = blockIdx.z;
    gemm_body<MODE_F32>(As, Bs, blockIdx.x, 0,
                        hout + z * 512, WoutT + z * 512, 8192, 8192, 512,
                        parts + (long long)z * 4096 * 64, 64, 64,
                        nullptr, nullptr, nullptr);
}

// masked online-softmax attention + ELU -> hout slice (bf16); wave per (row,head)
__global__ __launch_bounds__(256)
void attn_head(const __hip_bfloat16* __restrict__ Wh,
               const float2* __restrict__ f12,
               const unsigned* __restrict__ mask,
               const unsigned* __restrict__ summary,
               __hip_bfloat16* __restrict__ hout)
{
    const int wv   = threadIdx.x >> 6;
    const int lane = threadIdx.x & 63;
    const int i    = blockIdx.x * 4 + wv;
    const int h    = blockIdx.y;
    const float2* f = f12 + (long long)h * 4096;
    const float f1 = f[i].x;
    const unsigned* mrow = mask + (long long)i * 128;
    const __hip_bfloat16* WhH = Wh + (long long)h * 4096 * 1024;
    const uint4 sm = *(const uint4*)(summary + (long long)i * 4);
    unsigned sw[4] = { sm.x, sm.y, sm.z, sm.w };
    const int cbase = lane * 16;

    float m = -INFINITY, l = 0.f;
    float acc[16];
#pragma unroll
    for (int k = 0; k < 16; ++k) acc[k] = 0.f;

#pragma unroll
    for (int s = 0; s < 4; ++s) {
        unsigned sb = sw[s];
        while (sb) {
            const int w = s * 32 + __builtin_ctz(sb);
            sb &= sb - 1;
            unsigned bits = mrow[w];
            while (bits) {
                const int j = w * 32 + __builtin_ctz(bits);
                bits &= bits - 1;
                float e = f1 + f[j].y;
                e = e > 0.f ? e : 0.2f * e;           // leaky_relu 0.2
                float wgt;
                if (e > m) {
                    const float sc = __expf(m - e);   // 0 on first iter
                    l *= sc;
#pragma unroll
                    for (int k = 0; k < 16; ++k) acc[k] *= sc;
                    m = e; wgt = 1.f;
                } else {
                    wgt = __expf(e - m);
                }
                l += wgt;
                const ushort8* p = (const ushort8*)(WhH + (long long)j * 1024 + cbase);
                const ushort8 w0 = p[0], w1 = p[1];
#pragma unroll
                for (int k = 0; k < 8; ++k) acc[k]     += wgt * bfbits2f(w0[k]);
#pragma unroll
                for (int k = 0; k < 8; ++k) acc[k + 8] += wgt * bfbits2f(w1[k]);
            }
        }
    }
    const float inv = 1.f / l;
    ushort8 o0, o1;
#pragma unroll
    for (int k = 0; k < 8; ++k) {
        float v = acc[k] * inv;     v = v > 0.f ? v : (__expf(v) - 1.f); o0[k] = f2bfbits(v);
        float u = acc[k + 8] * inv; u = u > 0.f ? u : (__expf(u) - 1.f); o1[k] = f2bfbits(u);
    }
    ushort8* op = (ushort8*)(hout + (long long)i * 8192 + (long long)h * 1024 + cbase);
    op[0] = o0; op[1] = o1;
}

// sum 16 split-K parts -> Cout; fused f1o/f2o dot products (1 wave)
__global__ void out_reduce_f(const float* __restrict__ parts,
                             const float* __restrict__ a_out,
                             float* __restrict__ Cout,
                             float* __restrict__ f1o,
                             float* __restrict__ f2o)
{
    const int i = blockIdx.x, c = threadIdx.x;
    float v = 0.f;
#pragma unroll
    for (int z = 0; z < 16; ++z) v += parts[(long long)z * 4096 * 64 + (long long)i * 64 + c];
    Cout[(long long)i * 64 + c] = v;
    float s1 = v * a_out[c];
    float s2 = v * a_out[64 + c];
    for (int off = 32; off; off >>= 1) { s1 += __shfl_down(s1, off); s2 += __shfl_down(s2, off); }
    if (c == 0) { f1o[i] = s1; f2o[i] = s2; }
}

// final masked attention over Cout + tanh -> out (f32); wave per row
__global__ __launch_bounds__(256)
void attn_out(const float* __restrict__ Cout,
              const float* __restrict__ f1o,
              const float* __restrict__ f2o,
              const unsigned* __restrict__ mask,
              const unsigned* __restrict__ summary,
              float* __restrict__ out)
{
    const int wv = threadIdx.x >> 6;
    const int c  = threadIdx.x & 63;
    const int i  = blockIdx.x * 4 + wv;
    const float f1 = f1o[i];
    const unsigned* mrow = mask + (long long)i * 128;
    const uint4 sm = *(const uint4*)(summary + (long long)i * 4);
    unsigned sw[4] = { sm.x, sm.y, sm.z, sm.w };
    float m = -INFINITY, l = 0.f, acc = 0.f;
#pragma unroll
    for (int s = 0; s < 4; ++s) {
        unsigned sb = sw[s];
        while (sb) {
            const int w = s * 32 + __builtin_ctz(sb);
            sb &= sb - 1;
            unsigned bits = mrow[w];
            while (bits) {
                const int j = w * 32 + __builtin_ctz(bits);
                bits &= bits - 1;
                float e = f1 + f2o[j];
                e = e > 0.f ? e : 0.2f * e;
                float wgt;
                if (e > m) { const float sc = __expf(m - e); l *= sc; acc *= sc; m = e; wgt = 1.f; }
                else       { wgt = __expf(e - m); }
                l += wgt;
                acc += wgt * Cout[(long long)j * 64 + c];
            }
        }
    }
    out[(long long)i * 64 + c] = tanhf(acc / l);
}

extern "C" void kernel_launch(void* const* d_in, const int* in_sizes, int n_in,
                              void* d_out, int out_size, void* d_ws, size_t ws_size,
                              hipStream_t stream)
{
    (void)in_sizes; (void)n_in; (void)out_size;
    const float* x     = (const float*)d_in[0];
    const float* W_att = (const float*)d_in[1];
    const float* a_att = (const float*)d_in[2];
    const float* W_out = (const float*)d_in[3];
    const float* a_out = (const float*)d_in[4];
    float* out = (float*)d_out;

    char* ws = (char*)d_ws;
    size_t off = 0;
    auto alloc = [&](size_t bytes) -> void* {
        void* p = ws + off;
        off += (bytes + 255) & ~(size_t)255;
        return p;
    };

    __hip_bfloat16* x_bf  = (__hip_bfloat16*)alloc(4096LL * 1408 * 2);
    __hip_bfloat16* Wt_bf = (__hip_bfloat16*)alloc(8LL * 1024 * 1408 * 2);
    __hip_bfloat16* WoutT = (__hip_bfloat16*)alloc(128LL * 8192 * 2);
    float*          norms = (float*)alloc(4096 * 4);
    unsigned*       mask  = (unsigned*)alloc(4096LL * 128 * 4);   // contiguous with summ
    unsigned*       summ  = (unsigned*)alloc(4096LL * 4 * 4);
    float*          wa    = (float*)alloc(16LL * 1408 * 4);
    float2*         f12   = (float2*)alloc(8LL * 4096 * 8);
    float*          parts = (float*)alloc(16LL * 4096 * 64 * 4);
    float*          Cout  = (float*)alloc(4096LL * 64 * 4);
    float*          f1o   = (float*)alloc(4096 * 4);
    float*          f2o   = (float*)alloc(4096 * 4);
    __hip_bfloat16* Wh    = (__hip_bfloat16*)alloc(8LL * 4096 * 1024 * 2);
    __hip_bfloat16* hout  = (__hip_bfloat16*)alloc(8LL * 4096 * 1024 * 2);
    if (off > ws_size) return;   // ws too small (never observed; ~185 MB needed)

    // mask + summ are contiguous (both 256-aligned sizes): one memset
    hipMemsetAsync(mask, 0, 4096LL * 128 * 4 + 4096LL * 4 * 4, stream);

    prestage<<<19200, 256, 0, stream>>>(x, W_att, W_out, a_att,
                                        x_bf, norms, Wt_bf, WoutT, wa);

    mega_gemm<<<3600, 256, 0, stream>>>(x_bf, Wt_bf, Wh, norms, mask, summ,
                                        x, wa, f12);

    attn_head<<<dim3(1024, 8), 256, 0, stream>>>(Wh, f12, mask, summ, hout);

    out_gemm<<<dim3(32, 1, 16), 256, 0, stream>>>(hout, WoutT, parts);

    out_reduce_f<<<4096, 64, 0, stream>>>(parts, a_out, Cout, f1o, f2o);
    attn_out<<<1024, 256, 0, stream>>>(Cout, f1o, f2o, mask, summ, out);
}